// Round 9
// baseline (60.181 us; speedup 1.0000x reference)
//
#include <hip/hip_runtime.h>

#define D_IN  128
#define D_MID 256
#define D_OUT 16
#define NB    512
#define NN    8192
#define NROWS (NB + NN)   // 8704
#define BT    16          // query rows per KDE block
#define NSLICE 16         // n-slices for KDE
#define SLICE_N (NN / NSLICE)   // 512

typedef __attribute__((ext_vector_type(8))) short bf16x8;
typedef __attribute__((ext_vector_type(8))) unsigned short u16x8;
typedef __attribute__((ext_vector_type(4))) float f32x4;

// ---- ws layout (float offsets) ----
#define HID_OFF   0                         // hidden f32 [8704][256]
#define ZQ_OFF    2228224                   // zq f32 [512][16]
#define TARR_OFF  2236416                   // tarr f32 [8192][16]
#define ANEG_OFF  2367488                   // aneg f32 [8192][16]
#define PART_OFF  2498560                   // partial f32 [2*16][8192]
#define W2T_OFF   2760704                   // W2T f32 [64*16*4]
#define BF16_OFF  2764800                   // ushort region below (as ushort offsets):
#define W1HI_OFF  0                         // [256][128]
#define W1LO_OFF  32768
#define XHI_OFF   65536                     // [8704][128] (x ++ calc_X)
#define XLO_OFF   1179648

// round-to-nearest-even f32 -> bf16 hi, then bf16(residual) -> lo
__device__ inline void cvt_hilo(float f, unsigned short& hi, unsigned short& lo) {
    unsigned u = __builtin_bit_cast(unsigned, f);
    unsigned r = (u + 0x7FFFu + ((u >> 16) & 1u)) >> 16;
    hi = (unsigned short)r;
    const float fh = __builtin_bit_cast(float, r << 16);
    const float fl = f - fh;
    unsigned ul = __builtin_bit_cast(unsigned, fl);
    unsigned rl = (ul + 0x7FFFu + ((ul >> 16) & 1u)) >> 16;
    lo = (unsigned short)rl;
}

// ---------------- Kernel 0: convert W1, x|calc_X to bf16 hi/lo planes; W2 -> W2T ----
__global__ __launch_bounds__(256) void prep_kernel(
    const float* __restrict__ x, const float* __restrict__ calc_X,
    const float* __restrict__ W1, const float* __restrict__ W2,
    unsigned short* __restrict__ W1hi, unsigned short* __restrict__ W1lo,
    unsigned short* __restrict__ Xhi, unsigned short* __restrict__ Xlo,
    float* __restrict__ W2T)
{
    const int tid = blockIdx.x * 256 + threadIdx.x;   // 0..144383
    if (tid < 4096) {                                  // W1: 32768 elems / 8
        const size_t e = (size_t)tid * 8;
        const float4 a = reinterpret_cast<const float4*>(W1 + e)[0];
        const float4 b = reinterpret_cast<const float4*>(W1 + e)[1];
        const float f[8] = {a.x, a.y, a.z, a.w, b.x, b.y, b.z, b.w};
        u16x8 hv, lv;
#pragma unroll
        for (int i = 0; i < 8; ++i) { unsigned short h, l; cvt_hilo(f[i], h, l); hv[i] = h; lv[i] = l; }
        *reinterpret_cast<u16x8*>(W1hi + e) = hv;
        *reinterpret_cast<u16x8*>(W1lo + e) = lv;
    } else if (tid < 143360) {                         // X: 1114112 elems / 8
        const size_t e = (size_t)(tid - 4096) * 8;
        const float* src = (e < (size_t)NB * D_IN) ? (x + e) : (calc_X + e - (size_t)NB * D_IN);
        const float4 a = reinterpret_cast<const float4*>(src)[0];
        const float4 b = reinterpret_cast<const float4*>(src)[1];
        const float f[8] = {a.x, a.y, a.z, a.w, b.x, b.y, b.z, b.w};
        u16x8 hv, lv;
#pragma unroll
        for (int i = 0; i < 8; ++i) { unsigned short h, l; cvt_hilo(f[i], h, l); hv[i] = h; lv[i] = l; }
        *reinterpret_cast<u16x8*>(Xhi + e) = hv;
        *reinterpret_cast<u16x8*>(Xlo + e) = lv;
    } else {                                           // W2T: 1024 float4 transposes
        const int t2 = tid - 143360;
        const int j4 = t2 >> 4;
        const int d  = t2 & 15;
        const float4 v = reinterpret_cast<const float4*>(W2)[(size_t)d * 64 + j4];
        reinterpret_cast<float4*>(W2T)[(size_t)j4 * 16 + d] = v;
    }
}

// ---------------- Kernel 1: fc1 via MFMA split-bf16 ----------------
// 544 blocks = 136 row-tiles (64 rows) x 4 col-tiles (64 cols), 4 waves.
// Wave w: rows [row0+16w, +16); 4 n-subtiles x 4 k-steps x 3 mfma = 48 mfma.
__global__ __launch_bounds__(256) void fc1_kernel(
    const unsigned short* __restrict__ Xhi, const unsigned short* __restrict__ Xlo,
    const unsigned short* __restrict__ W1hi, const unsigned short* __restrict__ W1lo,
    float* __restrict__ hidden)
{
    const int t    = threadIdx.x;
    const int wv   = t >> 6;
    const int lane = t & 63;
    const int rb   = blockIdx.x >> 2;      // 0..135
    const int ch   = blockIdx.x & 3;       // 0..3 (64-col slice)
    const int l15  = lane & 15;
    const int kb   = lane >> 4;            // 0..3

    // A fragments: m = lane&15 (+16w), k = kstep*32 + kb*8 + i
    const int m = rb * 64 + wv * 16 + l15;
    bf16x8 ahi[4], alo[4];
#pragma unroll
    for (int ks = 0; ks < 4; ++ks) {
        const size_t off = (size_t)m * D_IN + ks * 32 + kb * 8;
        ahi[ks] = *reinterpret_cast<const bf16x8*>(Xhi + off);
        alo[ks] = *reinterpret_cast<const bf16x8*>(Xlo + off);
    }

    f32x4 acc[4];
#pragma unroll
    for (int nt = 0; nt < 4; ++nt) acc[nt] = f32x4{0.f, 0.f, 0.f, 0.f};

#pragma unroll
    for (int ks = 0; ks < 4; ++ks) {
        bf16x8 bhi[4], blo[4];
#pragma unroll
        for (int nt = 0; nt < 4; ++nt) {
            const int n = ch * 64 + nt * 16 + l15;   // n = lane&15 (+16nt)
            const size_t off = (size_t)n * D_IN + ks * 32 + kb * 8;
            bhi[nt] = *reinterpret_cast<const bf16x8*>(W1hi + off);
            blo[nt] = *reinterpret_cast<const bf16x8*>(W1lo + off);
        }
#pragma unroll
        for (int nt = 0; nt < 4; ++nt) {
            acc[nt] = __builtin_amdgcn_mfma_f32_16x16x32_bf16(ahi[ks], bhi[nt], acc[nt], 0, 0, 0);
            acc[nt] = __builtin_amdgcn_mfma_f32_16x16x32_bf16(alo[ks], bhi[nt], acc[nt], 0, 0, 0);
            acc[nt] = __builtin_amdgcn_mfma_f32_16x16x32_bf16(ahi[ks], blo[nt], acc[nt], 0, 0, 0);
        }
    }

    // C/D: col = lane&15, row = (lane>>4)*4 + reg  [verified layout]
    const int mrow = rb * 64 + wv * 16 + kb * 4;
#pragma unroll
    for (int nt = 0; nt < 4; ++nt) {
        const int n = ch * 64 + nt * 16 + l15;
#pragma unroll
        for (int r = 0; r < 4; ++r)
            hidden[(size_t)(mrow + r) * D_MID + n] = fmaxf(acc[nt][r], 0.f);
    }
}

// ---------------- Kernel 2: per-tile f32 spot-check + self-repair ----------------
// Same grid as fc1. Checks row row0+5 (cols of this block's slice) vs f32 dot;
// on mismatch recomputes the whole 64x64 tile in f32. Never triggers when the
// MFMA fragment layout is right; guarantees correctness when it isn't.
__global__ __launch_bounds__(256) void fcheck_kernel(
    const float* __restrict__ x, const float* __restrict__ calc_X,
    const float* __restrict__ W1, float* __restrict__ hidden)
{
    __shared__ int sflag;
    const int t    = threadIdx.x;
    const int rb   = blockIdx.x >> 2;
    const int ch   = blockIdx.x & 3;
    const int row0 = rb * 64;
    if (t == 0) sflag = 0;
    __syncthreads();

    if (t < 64) {
        const int r = row0 + 5;
        const int j = ch * 64 + t;
        const float* __restrict__ rowp = (r < NB) ? (x + (size_t)r * D_IN)
                                                  : (calc_X + (size_t)(r - NB) * D_IN);
        const float* __restrict__ w1r = W1 + (size_t)j * D_IN;
        float a = 0.f;
#pragma unroll 4
        for (int k = 0; k < D_IN; ++k) a = fmaf(rowp[k], w1r[k], a);
        a = fmaxf(a, 0.f);
        const float got = hidden[(size_t)r * D_MID + j];
        if (fabsf(a - got) > 1e-2f * fmaxf(1.f, fabsf(a))) sflag = 1;
    }
    __syncthreads();
    if (!sflag) return;

    // fallback: recompute this block's 64x64 tile in f32
    const int j = ch * 64 + (t & 63);
    const float* __restrict__ w1r = W1 + (size_t)j * D_IN;
    for (int rr = (t >> 6) * 16; rr < (t >> 6) * 16 + 16; ++rr) {
        const int r = row0 + rr;
        const float* __restrict__ rowp = (r < NB) ? (x + (size_t)r * D_IN)
                                                  : (calc_X + (size_t)(r - NB) * D_IN);
        float a = 0.f;
#pragma unroll 4
        for (int k = 0; k < D_IN; ++k) a = fmaf(rowp[k], w1r[k], a);
        hidden[(size_t)r * D_MID + j] = fmaxf(a, 0.f);
    }
}

// ---------------- Kernel 3: fc2 + scaled-embedding epilogue ----------------
// zs = s*(hidden_row @ W2^T).  query rows -> zq;  ref rows -> tarr = 2*zs, aneg = -zs^2.
__global__ __launch_bounds__(256) void fc2_kernel(
    const float* __restrict__ hidden, const float* __restrict__ W2T,
    const float* __restrict__ hptr,
    float* __restrict__ zq, float* __restrict__ tarr, float* __restrict__ aneg)
{
    const int t    = threadIdx.x;
    const int rloc = t >> 5;            // 0..7
    const int half = (t >> 4) & 1;
    const int d    = t & 15;
    const int r    = blockIdx.x * 8 + rloc;

    const float4* __restrict__ h4 =
        reinterpret_cast<const float4*>(hidden + (size_t)r * D_MID) + half * 32;
    const float4* __restrict__ w4 =
        reinterpret_cast<const float4*>(W2T) + half * 32 * 16;

    float4 a = make_float4(0.f, 0.f, 0.f, 0.f);
#pragma unroll 8
    for (int j4 = 0; j4 < 32; ++j4) {
        const float4 hv = h4[j4];
        const float4 wv = w4[j4 * 16 + d];
        a.x = fmaf(hv.x, wv.x, a.x);
        a.y = fmaf(hv.y, wv.y, a.y);
        a.z = fmaf(hv.z, wv.z, a.z);
        a.w = fmaf(hv.w, wv.w, a.w);
    }
    float v = (a.x + a.y) + (a.z + a.w);
    v += __shfl_xor(v, 16, 64);
    if (half == 0) {
        const float s = 0.84932180028801904272f / hptr[0];   // sqrt(log2(e)/2)/h
        const float z = v * s;
        if (r < NB) {
            zq[(size_t)r * D_OUT + d] = z;
        } else {
            const size_t k = (size_t)(r - NB) * D_OUT + d;
            tarr[k] = z + z;
            aneg[k] = -z * z;
        }
    }
}

// ---------------- Kernel 4: partial KDE sums, u = exp2(t*z + a) ----------------
// grid (NB/BT=32, NSLICE=16), 256 threads = 16 d x 16 chunk; scalar coalesced loads.
__global__ __launch_bounds__(256) void kde_kernel(
    const float* __restrict__ zq, const float* __restrict__ tarr,
    const float* __restrict__ aneg, const float* __restrict__ Y,
    float* __restrict__ partial)
{
    __shared__ float red[4][16][32];   // [wave][d][bt*2 + {num,den}]

    const int t     = threadIdx.x;
    const int d     = t & 15;
    const int chunk = t >> 4;          // 0..15
    const int b0    = blockIdx.x * BT;
    const int slice = blockIdx.y;

    float z[BT], num[BT] = {}, den[BT] = {};
#pragma unroll
    for (int bt = 0; bt < BT; ++bt)
        z[bt] = zq[(size_t)(b0 + bt) * D_OUT + d];

#pragma unroll 2
    for (int i = 0; i < SLICE_N / 16; ++i) {        // 32 iterations
        const size_t n = (size_t)slice * SLICE_N + i * 16 + chunk;
        const float tv = tarr[n * D_OUT + d];       // 4B/lane, fully coalesced
        const float av = aneg[n * D_OUT + d];
        const float yv = Y[n * D_OUT + d];
#pragma unroll
        for (int bt = 0; bt < BT; ++bt) {
            const float e = fmaf(tv, z[bt], av);
            const float u = __builtin_amdgcn_exp2f(e);
            den[bt] += u;
            num[bt] = fmaf(u, yv, num[bt]);
        }
    }

    // ---- reduce over chunk lanes within wave: xor 16, 32 ----
    float vals[32];
#pragma unroll
    for (int bt = 0; bt < BT; ++bt) {
        vals[bt * 2 + 0] = num[bt];
        vals[bt * 2 + 1] = den[bt];
    }
#pragma unroll
    for (int m = 16; m <= 32; m <<= 1) {
#pragma unroll
        for (int v = 0; v < 32; ++v)
            vals[v] += __shfl_xor(vals[v], m, 64);
    }

    const int wave = t >> 6;
    if ((t & 63) < 16) {
#pragma unroll
        for (int v = 0; v < 32; ++v) red[wave][d][v] = vals[v];
    }
    __syncthreads();

    // ---- 512 outputs: o = bt(16) x d(16) x p(2), 2 per thread ----
#pragma unroll
    for (int rep = 0; rep < 2; ++rep) {
        const int o  = rep * 256 + t;
        const int p  = o & 1;
        const int dd = (o >> 1) & 15;
        const int bt = o >> 5;
        const int v  = bt * 2 + p;
        const float sum = red[0][dd][v] + red[1][dd][v] + red[2][dd][v] + red[3][dd][v];
        partial[(size_t)(p * NSLICE + slice) * NB * D_OUT + (size_t)(b0 + bt) * D_OUT + dd] = sum;
    }
}

// ---------------- Kernel 5: combine slices + divide ----------------
__global__ __launch_bounds__(256) void combine_kernel(
    const float* __restrict__ partial, float* __restrict__ out)
{
    const int i = blockIdx.x * 256 + threadIdx.x;   // 0..8191
    float nsum = 0.f, dsum = 0.f;
#pragma unroll
    for (int s = 0; s < NSLICE; ++s) {
        nsum += partial[(size_t)s * NB * D_OUT + i];
        dsum += partial[(size_t)(NSLICE + s) * NB * D_OUT + i];
    }
    out[i] = nsum / dsum;
}

extern "C" void kernel_launch(void* const* d_in, const int* in_sizes, int n_in,
                              void* d_out, int out_size, void* d_ws, size_t ws_size,
                              hipStream_t stream) {
    const float* x      = (const float*)d_in[0];
    const float* calc_X = (const float*)d_in[1];
    const float* calc_Y = (const float*)d_in[2];
    const float* W1     = (const float*)d_in[3];
    const float* W2     = (const float*)d_in[4];
    const float* h      = (const float*)d_in[5];

    float* ws      = (float*)d_ws;
    float* hidden  = ws + HID_OFF;
    float* zq      = ws + ZQ_OFF;
    float* tarr    = ws + TARR_OFF;
    float* aneg    = ws + ANEG_OFF;
    float* partial = ws + PART_OFF;
    float* W2T     = ws + W2T_OFF;
    unsigned short* bf = (unsigned short*)(ws + BF16_OFF);
    unsigned short* W1hi = bf + W1HI_OFF;
    unsigned short* W1lo = bf + W1LO_OFF;
    unsigned short* Xhi  = bf + XHI_OFF;
    unsigned short* Xlo  = bf + XLO_OFF;
    float* out = (float*)d_out;

    prep_kernel<<<dim3(564), dim3(256), 0, stream>>>(x, calc_X, W1, W2,
                                                     W1hi, W1lo, Xhi, Xlo, W2T);
    fc1_kernel<<<dim3(544), dim3(256), 0, stream>>>(Xhi, Xlo, W1hi, W1lo, hidden);
    fcheck_kernel<<<dim3(544), dim3(256), 0, stream>>>(x, calc_X, W1, hidden);
    fc2_kernel<<<dim3(NROWS / 8), dim3(256), 0, stream>>>(hidden, W2T, h, zq, tarr, aneg);
    kde_kernel<<<dim3(NB / BT, NSLICE), dim3(256), 0, stream>>>(zq, tarr, aneg, calc_Y, partial);
    combine_kernel<<<dim3(NB * D_OUT / 256), dim3(256), 0, stream>>>(partial, out);
}